// Round 6
// baseline (404.762 us; speedup 1.0000x reference)
//
#include <hip/hip_runtime.h>

#define NGRID 8192
#define NLAYER 24
#define NPERIODS 50
#define NOBS 4096
#define NC 200
#define PP 64            // periods padded to 64 (r_pad layout)
#define NSPLIT 16        // g-splits across blockIdx.y in K2 (R5's 32 regressed: revert)
#define SPLITG (NGRID / NSPLIT)       // 512 g per split
#define WPB 4            // waves per block in K2
#define GC (SPLITG / WPB)             // 128 g per wave
#define KG 16            // g subtile staged in LDS per wave
#define ASTR 20          // A-tile LDS stride (floats): conflicts measured negligible
#define RSTR 64          // r-tile LDS stride (floats): uniform broadcast reads, conflict-free
#define DOT 128          // obs per block: each wave holds TWO 64-obs acc tiles
#define NBINS 1024
#define VREF 3.0f
#define WLDSF (DOT * ASTR + KG * RSTR)   // per-wave floats: 2560 + 1024 = 3584
#define K2LDSF (WPB * WLDSF)             // 14336 floats = 57344 B -> 2 blocks/CU

// ---------------- K1: r_pad[g][p] = 1/(0.92 * sum_l w[p][l]*Vs[g][l]); block 0 zeroes bins ----
__global__ __launch_bounds__(256) void k1_rpad(const float* __restrict__ Vs,
                                               const float* __restrict__ thick,
                                               const float* __restrict__ periods,
                                               float* __restrict__ r_pad,
                                               float* __restrict__ bins) {
    __shared__ float w_sh[NLAYER][NPERIODS];   // transposed: reads are conflict-free
    __shared__ float z_sh[NLAYER];
    int tid = threadIdx.x;
    if (blockIdx.x == 0) {
        for (int i = tid; i < NBINS; i += 256) bins[i] = 0.f;
    }
    if (tid < NLAYER) {
        float c = 0.f;
        for (int i = 0; i <= tid; ++i) c += thick[i];
        z_sh[tid] = c - 0.5f * thick[tid];
    }
    __syncthreads();
    if (tid < NPERIODS) {
        float ds = (VREF / 3.0f) * periods[tid];
        float tmp[NLAYER];
        float s = 0.f;
        #pragma unroll
        for (int l = 0; l < NLAYER; ++l) {
            float v = expf(-z_sh[l] / ds) * thick[l];
            tmp[l] = v; s += v;
        }
        float inv = 1.f / s;
        #pragma unroll
        for (int l = 0; l < NLAYER; ++l) w_sh[l][tid] = tmp[l] * inv;
    }
    __syncthreads();
    int idx = blockIdx.x * 256 + tid;          // idx = g*64 + p  (lanes share g -> broadcast Vs)
    int g = idx >> 6, p = idx & 63;
    float r = 0.f;
    if (p < NPERIODS) {
        const float4* vp = (const float4*)(Vs + (size_t)g * NLAYER);
        float s = 0.f;
        #pragma unroll
        for (int q = 0; q < NLAYER / 4; ++q) {
            float4 t = vp[q];
            s = fmaf(w_sh[4*q+0][p], t.x, s);
            s = fmaf(w_sh[4*q+1][p], t.y, s);
            s = fmaf(w_sh[4*q+2][p], t.z, s);
            s = fmaf(w_sh[4*q+3][p], t.w, s);
        }
        r = 1.0f / (0.92f * s);
    }
    r_pad[idx] = r;                            // fully coalesced, zero-padded p>=50
}

// ---------------- K2: partial[s][o][p] = sum_{g in split s} A[o][g]*r[g][p] ----------------
// R5 evidence: +26% occupancy -> 0% speedup; per-wave duty ~13% => the r-row path
// (wave-uniform s_load, 50 SGPRs/row, SMEM out-of-order -> lgkmcnt(0) full drains,
// no SGPR budget to pipeline) serializes the inner loop. R6: r-rows now staged in
// wave-private LDS and read via uniform-address ds_read_b128 BROADCASTS (in-order DS
// -> partial lgkmcnt waits, ~120cy, VGPR-funded). Both A and r staging are
// register-double-buffered: next kt's 12 global float4 loads issue before the inner
// loop; vmcnt latency hides under ~3200cy of FMAs. Same-wave DS ordering -> no barriers.
__global__ __launch_bounds__(256) void k2_gemm(const float* __restrict__ A,
                                               const float* __restrict__ r_pad,
                                               float* __restrict__ partial) {
    __shared__ float lds[K2LDSF];              // 57344 B
    int tid  = threadIdx.x;
    int lane = tid & 63;
    int wv   = __builtin_amdgcn_readfirstlane(tid >> 6);
    int o_base = blockIdx.x * DOT;
    int split  = blockIdx.y;
    float* Aw = lds + wv * WLDSF;
    float* Rw = Aw + DOT * ASTR;

    float acc0[NPERIODS], acc1[NPERIODS];
    #pragma unroll
    for (int p = 0; p < NPERIODS; ++p) { acc0[p] = 0.f; acc1[p] = 0.f; }

    int g_wave = split * SPLITG + wv * GC;

    // register staging buffers (statically indexed -> stay in VGPRs)
    float4 aS[8], rS[4];
    // prologue: load kt=0 chunk
    #pragma unroll
    for (int s = 0; s < 8; ++s)
        aS[s] = *(const float4*)(A + (size_t)(o_base + s * 16 + (lane >> 2)) * NGRID
                                 + g_wave + (lane & 3) * 4);
    #pragma unroll
    for (int s = 0; s < 4; ++s)
        rS[s] = *(const float4*)(r_pad + (size_t)(g_wave + s * 4 + (lane >> 4)) * PP
                                 + (lane & 15) * 4);

    #pragma unroll 1
    for (int kt = 0; kt < GC / KG; ++kt) {                 // 8 subtiles of 16 g
        // commit staged regs to wave-private LDS (compiler waits vmcnt here)
        #pragma unroll
        for (int s = 0; s < 8; ++s)
            *(float4*)(Aw + (s * 16 + (lane >> 2)) * ASTR + (lane & 3) * 4) = aS[s];
        #pragma unroll
        for (int s = 0; s < 4; ++s)
            *(float4*)(Rw + (s * 64 + lane) * 4) = rS[s];   // linear: Rw[g][64], g=e>>4

        // prefetch next kt into regs (latency hides under this kt's FMAs)
        if (kt + 1 < GC / KG) {
            int gn = g_wave + (kt + 1) * KG;
            #pragma unroll
            for (int s = 0; s < 8; ++s)
                aS[s] = *(const float4*)(A + (size_t)(o_base + s * 16 + (lane >> 2)) * NGRID
                                         + gn + (lane & 3) * 4);
            #pragma unroll
            for (int s = 0; s < 4; ++s)
                rS[s] = *(const float4*)(r_pad + (size_t)(gn + s * 4 + (lane >> 4)) * PP
                                         + (lane & 15) * 4);
        }

        // inner: pure DS + FMA (single in-order lgkm class -> deep pipelining)
        #pragma unroll 1
        for (int gg = 0; gg < KG; gg += 4) {
            float4 a0 = *(const float4*)(Aw + lane * ASTR + gg);
            float4 a1 = *(const float4*)(Aw + (64 + lane) * ASTR + gg);
            #pragma unroll
            for (int j = 0; j < 4; ++j) {
                float aj0 = (j == 0) ? a0.x : (j == 1) ? a0.y : (j == 2) ? a0.z : a0.w;
                float aj1 = (j == 0) ? a1.x : (j == 1) ? a1.y : (j == 2) ? a1.z : a1.w;
                const float* rj = Rw + (gg + j) * RSTR;    // uniform LDS addr -> broadcast
                #pragma unroll
                for (int q = 0; q < 12; ++q) {
                    float4 rv = *(const float4*)(rj + 4 * q);   // ds_read_b128 broadcast
                    acc0[4*q+0] = fmaf(aj0, rv.x, acc0[4*q+0]);
                    acc0[4*q+1] = fmaf(aj0, rv.y, acc0[4*q+1]);
                    acc0[4*q+2] = fmaf(aj0, rv.z, acc0[4*q+2]);
                    acc0[4*q+3] = fmaf(aj0, rv.w, acc0[4*q+3]);
                    acc1[4*q+0] = fmaf(aj1, rv.x, acc1[4*q+0]);
                    acc1[4*q+1] = fmaf(aj1, rv.y, acc1[4*q+1]);
                    acc1[4*q+2] = fmaf(aj1, rv.z, acc1[4*q+2]);
                    acc1[4*q+3] = fmaf(aj1, rv.w, acc1[4*q+3]);
                }
                float2 rv2 = *(const float2*)(rj + 48);
                acc0[48] = fmaf(aj0, rv2.x, acc0[48]);
                acc0[49] = fmaf(aj0, rv2.y, acc0[49]);
                acc1[48] = fmaf(aj1, rv2.x, acc1[48]);
                acc1[49] = fmaf(aj1, rv2.y, acc1[49]);
            }
        }
    }

    // epilogue: cross-wave reduce (4 waves, same 128 obs) in 4 fully-unrolled phases of 16 p
    float* outp = partial + (size_t)split * (NOBS * NPERIODS) + (size_t)o_base * NPERIODS;
    #pragma unroll
    for (int h = 0; h < 4; ++h) {
        __syncthreads();
        float* rw = lds + wv * (DOT * 17);                 // stride 17 (odd) -> conflict-free
        #pragma unroll
        for (int q = 0; q < 16; ++q) {
            int p = h * 16 + q;
            rw[lane * 17 + q]        = (p < NPERIODS) ? acc0[p] : 0.f;
            rw[(64 + lane) * 17 + q] = (p < NPERIODS) ? acc1[p] : 0.f;
        }
        __syncthreads();
        for (int e = tid; e < DOT * 16; e += 256) {
            int oo = e >> 4, q = e & 15;
            int p  = h * 16 + q;
            if (p < NPERIODS) {
                float v = 0.f;
                #pragma unroll
                for (int w2 = 0; w2 < WPB; ++w2) v += lds[w2 * (DOT * 17) + oo * 17 + q];
                outp[oo * NPERIODS + p] = v;
            }
        }
    }
}

// ---------------- K3: block per obs; fused k2b (cpred for own obs via LDS), ballot
//                      searchsorted, shuffle interp. No fences. ----------------
__global__ __launch_bounds__(256) void k3_main(const float* __restrict__ energy,
                                               const float* __restrict__ c_axis,
                                               const float* __restrict__ partial,
                                               float* __restrict__ bins) {
    __shared__ float csh[NC];
    __shared__ float cp_sh[64];
    __shared__ float red[4];
    int tid  = threadIdx.x;
    int lane = tid & 63;
    int wv   = tid >> 6;
    int o    = blockIdx.x;

    if (tid < NC) csh[tid] = c_axis[(size_t)o * NC + tid];
    // fused k2b: cpred for THIS obs only (16x50 coalesced loads; kernel boundary = sync)
    if (tid >= 192) {
        int p = tid - 192;
        float v = 0.f;
        if (p < NPERIODS) {
            float s = 0.f;
            #pragma unroll
            for (int sp = 0; sp < NSPLIT; ++sp)
                s += partial[(size_t)sp * (NOBS * NPERIODS) + (size_t)o * NPERIODS + p];
            v = 1.0f / s;
        }
        cp_sh[p] = v;
    }
    __syncthreads();

    bool act = lane < NC / 4;                  // 50 active lanes
    float4 ca = act ? *(const float4*)(csh + 4 * lane) : make_float4(9e30f, 9e30f, 9e30f, 9e30f);
    const float* ebase = energy + (size_t)o * NPERIODS * NC;
    float local = 0.f;

    for (int p0 = wv; p0 < NPERIODS; p0 += 8) {
        int p1 = p0 + 4;
        bool has1 = p1 < NPERIODS;
        int p1c = has1 ? p1 : p0;
        float cpA = cp_sh[p0];
        float cpB = cp_sh[p1c];
        const float* erA = ebase + (size_t)p0 * NC;
        const float* erB = ebase + (size_t)p1c * NC;
        float4 eA = act ? *(const float4*)(erA + 4 * lane) : make_float4(-1e30f, -1e30f, -1e30f, -1e30f);
        float4 eB = act ? *(const float4*)(erB + 4 * lane) : make_float4(-1e30f, -1e30f, -1e30f, -1e30f);

        // searchsorted 'left' = count(c_axis < cp) via ballot+popcount
        int cntA = __popcll(__ballot(ca.x < cpA)) + __popcll(__ballot(ca.y < cpA))
                 + __popcll(__ballot(ca.z < cpA)) + __popcll(__ballot(ca.w < cpA));
        int cntB = __popcll(__ballot(ca.x < cpB)) + __popcll(__ballot(ca.y < cpB))
                 + __popcll(__ballot(ca.z < cpB)) + __popcll(__ballot(ca.w < cpB));

        // row max: butterfly, two independent chains interleaved
        float mA = fmaxf(fmaxf(eA.x, eA.y), fmaxf(eA.z, eA.w));
        float mB = fmaxf(fmaxf(eB.x, eB.y), fmaxf(eB.z, eB.w));
        #pragma unroll
        for (int m = 32; m; m >>= 1) {
            mA = fmaxf(mA, __shfl_xor(mA, m, 64));
            mB = fmaxf(mB, __shfl_xor(mB, m, 64));
        }

        int iA = cntA < 1 ? 1 : (cntA > NC - 1 ? NC - 1 : cntA);
        int iB = cntB < 1 ? 1 : (cntB > NC - 1 ? NC - 1 : cntB);

        // e0/e1 fetched from registers by shuffle (idx is wave-uniform)
        int a0 = iA - 1, a1 = iA, b0 = iB - 1, b1 = iB;
        float sA0 = ((a0 & 3) == 0) ? eA.x : ((a0 & 3) == 1) ? eA.y : ((a0 & 3) == 2) ? eA.z : eA.w;
        float sA1 = ((a1 & 3) == 0) ? eA.x : ((a1 & 3) == 1) ? eA.y : ((a1 & 3) == 2) ? eA.z : eA.w;
        float sB0 = ((b0 & 3) == 0) ? eB.x : ((b0 & 3) == 1) ? eB.y : ((b0 & 3) == 2) ? eB.z : eB.w;
        float sB1 = ((b1 & 3) == 0) ? eB.x : ((b1 & 3) == 1) ? eB.y : ((b1 & 3) == 2) ? eB.z : eB.w;
        float e0A = __shfl(sA0, a0 >> 2, 64), e1A = __shfl(sA1, a1 >> 2, 64);
        float e0B = __shfl(sB0, b0 >> 2, 64), e1B = __shfl(sB1, b1 >> 2, 64);

        float c0A = csh[a0], c1A = csh[a1];
        float c0B = csh[b0], c1B = csh[b1];
        float wA = (cpA - c0A) / (c1A - c0A + 1e-12f);
        float wB = (cpB - c0B) / (c1B - c0B + 1e-12f);
        float eiA = fmaf(wA, e1A - e0A, e0A);
        float eiB = fmaf(wB, e1B - e0B, e0B);
        local += mA - eiA;
        local += has1 ? (mB - eiB) : 0.f;
    }
    // every lane holds the identical wave-uniform sum
    if (lane == 0) red[wv] = local;
    __syncthreads();
    if (tid == 0)
        atomicAdd(&bins[blockIdx.x & (NBINS - 1)], red[0] + red[1] + red[2] + red[3]);
}

// ---------------- K4: final reduce of bins -> out ----------------
__global__ __launch_bounds__(256) void k4_final(const float* __restrict__ bins,
                                                float* __restrict__ out) {
    __shared__ float red[4];
    int tid = threadIdx.x;
    float s = 0.f;
    for (int i = tid; i < NBINS; i += 256) s += bins[i];
    #pragma unroll
    for (int m = 32; m; m >>= 1) s += __shfl_xor(s, m, 64);
    int lane = tid & 63, wv = tid >> 6;
    if (lane == 0) red[wv] = s;
    __syncthreads();
    if (tid == 0) out[0] = -(red[0] + red[1] + red[2] + red[3]);  // / SIGMA^2 == 1
}

extern "C" void kernel_launch(void* const* d_in, const int* in_sizes, int n_in,
                              void* d_out, int out_size, void* d_ws, size_t ws_size,
                              hipStream_t stream) {
    const float* Vs      = (const float*)d_in[0];
    const float* A       = (const float*)d_in[1];
    const float* energy  = (const float*)d_in[2];
    const float* c_axis  = (const float*)d_in[3];
    const float* thick   = (const float*)d_in[4];
    const float* periods = (const float*)d_in[5];
    float* out = (float*)d_out;

    float* ws      = (float*)d_ws;
    float* r_pad   = ws;                                        // 2 MB
    float* partial = r_pad + (size_t)NGRID * PP;                // 16*4096*50*4 = 13.1 MB
    float* bins    = partial + (size_t)NSPLIT * NOBS * NPERIODS;// 4 KB

    hipLaunchKernelGGL(k1_rpad, dim3((NGRID * 64) / 256), dim3(256), 0, stream,
                       Vs, thick, periods, r_pad, bins);
    hipLaunchKernelGGL(k2_gemm, dim3(NOBS / DOT, NSPLIT), dim3(256), 0, stream,
                       A, r_pad, partial);
    hipLaunchKernelGGL(k3_main, dim3(NOBS), dim3(256), 0, stream,
                       energy, c_axis, partial, bins);
    hipLaunchKernelGGL(k4_final, dim3(1), dim3(256), 0, stream, bins, out);
}

// Round 7
// 393.662 us; speedup vs baseline: 1.0282x; 1.0282x over previous
//
#include <hip/hip_runtime.h>

#define NGRID 8192
#define NLAYER 24
#define NPERIODS 50
#define NOBS 4096
#define NC 200
#define PP 64            // periods padded to 64 (r_pad layout)
#define NSPLIT 16        // g-splits across blockIdx.y in K2
#define SPLITG (NGRID / NSPLIT)       // 512 g per split
#define WPB 4            // waves per block in K2
#define GC (SPLITG / WPB)             // 128 g per wave
#define KG 16            // g subtile staged in LDS per wave
#define ASTR 20          // A-tile LDS stride (floats): conflicts measured negligible
#define RSTR 64          // r-tile LDS stride (floats): uniform broadcast reads, conflict-free
#define DOT 128          // obs per block: each wave holds TWO 64-obs acc tiles
#define NBINS 1024
#define VREF 3.0f
#define WLDSF (DOT * ASTR + KG * RSTR)   // per-wave floats: 2560 + 1024 = 3584
#define K2LDSF (WPB * WLDSF)             // 14336 floats = 57344 B -> 2 blocks/CU

// ---------------- K1: r_pad[g][p] = 1/(0.92 * sum_l w[p][l]*Vs[g][l]); block 0 zeroes bins ----
__global__ __launch_bounds__(256) void k1_rpad(const float* __restrict__ Vs,
                                               const float* __restrict__ thick,
                                               const float* __restrict__ periods,
                                               float* __restrict__ r_pad,
                                               float* __restrict__ bins) {
    __shared__ float w_sh[NLAYER][NPERIODS];   // transposed: reads are conflict-free
    __shared__ float z_sh[NLAYER];
    int tid = threadIdx.x;
    if (blockIdx.x == 0) {
        for (int i = tid; i < NBINS; i += 256) bins[i] = 0.f;
    }
    if (tid < NLAYER) {
        float c = 0.f;
        for (int i = 0; i <= tid; ++i) c += thick[i];
        z_sh[tid] = c - 0.5f * thick[tid];
    }
    __syncthreads();
    if (tid < NPERIODS) {
        float ds = (VREF / 3.0f) * periods[tid];
        float tmp[NLAYER];
        float s = 0.f;
        #pragma unroll
        for (int l = 0; l < NLAYER; ++l) {
            float v = expf(-z_sh[l] / ds) * thick[l];
            tmp[l] = v; s += v;
        }
        float inv = 1.f / s;
        #pragma unroll
        for (int l = 0; l < NLAYER; ++l) w_sh[l][tid] = tmp[l] * inv;
    }
    __syncthreads();
    int idx = blockIdx.x * 256 + tid;          // idx = g*64 + p  (lanes share g -> broadcast Vs)
    int g = idx >> 6, p = idx & 63;
    float r = 0.f;
    if (p < NPERIODS) {
        const float4* vp = (const float4*)(Vs + (size_t)g * NLAYER);
        float s = 0.f;
        #pragma unroll
        for (int q = 0; q < NLAYER / 4; ++q) {
            float4 t = vp[q];
            s = fmaf(w_sh[4*q+0][p], t.x, s);
            s = fmaf(w_sh[4*q+1][p], t.y, s);
            s = fmaf(w_sh[4*q+2][p], t.z, s);
            s = fmaf(w_sh[4*q+3][p], t.w, s);
        }
        r = 1.0f / (0.92f * s);
    }
    r_pad[idx] = r;                            // fully coalesced, zero-padded p>=50
}

// ---------------- K2: partial[s][o][p] = sum_{g in split s} A[o][g]*r[g][p] ----------------
// R6 structure (dual-o-tile + reg-double-buffered staging + wave-private LDS r-broadcast)
// was correct but the compiler, with no min-waves bound, capped VGPR at 96 and spilled
// the ~170 live regs -> 141 MB scratch writes -> HBM-bound at 121us (bytes/BW closes).
// R7 fix: __launch_bounds__(256, 2) = 2 waves/EU = 2 blocks/CU (LDS 57KB caps there
// anyway) -> VGPR ceiling 256, no spill. r-rows read via uniform-address ds_read_b128
// broadcasts (in-order DS class, partial lgkm waits, conflict-free); A+r staging loads
// for kt+1 issue before kt's FMAs so vmcnt latency hides under ~3200cy of compute.
__global__ __launch_bounds__(256, 2) void k2_gemm(const float* __restrict__ A,
                                                  const float* __restrict__ r_pad,
                                                  float* __restrict__ partial) {
    __shared__ float lds[K2LDSF];              // 57344 B
    int tid  = threadIdx.x;
    int lane = tid & 63;
    int wv   = __builtin_amdgcn_readfirstlane(tid >> 6);
    int o_base = blockIdx.x * DOT;
    int split  = blockIdx.y;
    float* Aw = lds + wv * WLDSF;
    float* Rw = Aw + DOT * ASTR;

    float acc0[NPERIODS], acc1[NPERIODS];
    #pragma unroll
    for (int p = 0; p < NPERIODS; ++p) { acc0[p] = 0.f; acc1[p] = 0.f; }

    int g_wave = split * SPLITG + wv * GC;

    // register staging buffers (statically indexed -> stay in VGPRs; 48 VGPRs)
    float4 aS[8], rS[4];
    // prologue: load kt=0 chunk
    #pragma unroll
    for (int s = 0; s < 8; ++s)
        aS[s] = *(const float4*)(A + (size_t)(o_base + s * 16 + (lane >> 2)) * NGRID
                                 + g_wave + (lane & 3) * 4);
    #pragma unroll
    for (int s = 0; s < 4; ++s)
        rS[s] = *(const float4*)(r_pad + (size_t)(g_wave + s * 4 + (lane >> 4)) * PP
                                 + (lane & 15) * 4);

    #pragma unroll 1
    for (int kt = 0; kt < GC / KG; ++kt) {                 // 8 subtiles of 16 g
        // commit staged regs to wave-private LDS (compiler waits vmcnt here)
        #pragma unroll
        for (int s = 0; s < 8; ++s)
            *(float4*)(Aw + (s * 16 + (lane >> 2)) * ASTR + (lane & 3) * 4) = aS[s];
        #pragma unroll
        for (int s = 0; s < 4; ++s)
            *(float4*)(Rw + (s * 64 + lane) * 4) = rS[s];   // linear: Rw[g][64]

        // prefetch next kt into regs (latency hides under this kt's FMAs)
        if (kt + 1 < GC / KG) {
            int gn = g_wave + (kt + 1) * KG;
            #pragma unroll
            for (int s = 0; s < 8; ++s)
                aS[s] = *(const float4*)(A + (size_t)(o_base + s * 16 + (lane >> 2)) * NGRID
                                         + gn + (lane & 3) * 4);
            #pragma unroll
            for (int s = 0; s < 4; ++s)
                rS[s] = *(const float4*)(r_pad + (size_t)(gn + s * 4 + (lane >> 4)) * PP
                                         + (lane & 15) * 4);
        }

        // inner: pure DS + FMA (single in-order lgkm class -> deep pipelining)
        #pragma unroll 1
        for (int gg = 0; gg < KG; gg += 4) {
            float4 a0 = *(const float4*)(Aw + lane * ASTR + gg);
            float4 a1 = *(const float4*)(Aw + (64 + lane) * ASTR + gg);
            #pragma unroll
            for (int j = 0; j < 4; ++j) {
                float aj0 = (j == 0) ? a0.x : (j == 1) ? a0.y : (j == 2) ? a0.z : a0.w;
                float aj1 = (j == 0) ? a1.x : (j == 1) ? a1.y : (j == 2) ? a1.z : a1.w;
                const float* rj = Rw + (gg + j) * RSTR;    // uniform LDS addr -> broadcast
                #pragma unroll
                for (int q = 0; q < 12; ++q) {
                    float4 rv = *(const float4*)(rj + 4 * q);   // ds_read_b128 broadcast
                    acc0[4*q+0] = fmaf(aj0, rv.x, acc0[4*q+0]);
                    acc0[4*q+1] = fmaf(aj0, rv.y, acc0[4*q+1]);
                    acc0[4*q+2] = fmaf(aj0, rv.z, acc0[4*q+2]);
                    acc0[4*q+3] = fmaf(aj0, rv.w, acc0[4*q+3]);
                    acc1[4*q+0] = fmaf(aj1, rv.x, acc1[4*q+0]);
                    acc1[4*q+1] = fmaf(aj1, rv.y, acc1[4*q+1]);
                    acc1[4*q+2] = fmaf(aj1, rv.z, acc1[4*q+2]);
                    acc1[4*q+3] = fmaf(aj1, rv.w, acc1[4*q+3]);
                }
                float2 rv2 = *(const float2*)(rj + 48);
                acc0[48] = fmaf(aj0, rv2.x, acc0[48]);
                acc0[49] = fmaf(aj0, rv2.y, acc0[49]);
                acc1[48] = fmaf(aj1, rv2.x, acc1[48]);
                acc1[49] = fmaf(aj1, rv2.y, acc1[49]);
            }
        }
    }

    // epilogue: cross-wave reduce (4 waves, same 128 obs) in 4 fully-unrolled phases of 16 p
    float* outp = partial + (size_t)split * (NOBS * NPERIODS) + (size_t)o_base * NPERIODS;
    #pragma unroll
    for (int h = 0; h < 4; ++h) {
        __syncthreads();
        float* rw = lds + wv * (DOT * 17);                 // stride 17 (odd) -> conflict-free
        #pragma unroll
        for (int q = 0; q < 16; ++q) {
            int p = h * 16 + q;
            rw[lane * 17 + q]        = (p < NPERIODS) ? acc0[p] : 0.f;
            rw[(64 + lane) * 17 + q] = (p < NPERIODS) ? acc1[p] : 0.f;
        }
        __syncthreads();
        for (int e = tid; e < DOT * 16; e += 256) {
            int oo = e >> 4, q = e & 15;
            int p  = h * 16 + q;
            if (p < NPERIODS) {
                float v = 0.f;
                #pragma unroll
                for (int w2 = 0; w2 < WPB; ++w2) v += lds[w2 * (DOT * 17) + oo * 17 + q];
                outp[oo * NPERIODS + p] = v;
            }
        }
    }
}

// ---------------- K3: block per obs; fused k2b (cpred for own obs via LDS), ballot
//                      searchsorted, shuffle interp. No fences. ----------------
__global__ __launch_bounds__(256) void k3_main(const float* __restrict__ energy,
                                               const float* __restrict__ c_axis,
                                               const float* __restrict__ partial,
                                               float* __restrict__ bins) {
    __shared__ float csh[NC];
    __shared__ float cp_sh[64];
    __shared__ float red[4];
    int tid  = threadIdx.x;
    int lane = tid & 63;
    int wv   = tid >> 6;
    int o    = blockIdx.x;

    if (tid < NC) csh[tid] = c_axis[(size_t)o * NC + tid];
    // fused k2b: cpred for THIS obs only (16x50 coalesced loads; kernel boundary = sync)
    if (tid >= 192) {
        int p = tid - 192;
        float v = 0.f;
        if (p < NPERIODS) {
            float s = 0.f;
            #pragma unroll
            for (int sp = 0; sp < NSPLIT; ++sp)
                s += partial[(size_t)sp * (NOBS * NPERIODS) + (size_t)o * NPERIODS + p];
            v = 1.0f / s;
        }
        cp_sh[p] = v;
    }
    __syncthreads();

    bool act = lane < NC / 4;                  // 50 active lanes
    float4 ca = act ? *(const float4*)(csh + 4 * lane) : make_float4(9e30f, 9e30f, 9e30f, 9e30f);
    const float* ebase = energy + (size_t)o * NPERIODS * NC;
    float local = 0.f;

    for (int p0 = wv; p0 < NPERIODS; p0 += 8) {
        int p1 = p0 + 4;
        bool has1 = p1 < NPERIODS;
        int p1c = has1 ? p1 : p0;
        float cpA = cp_sh[p0];
        float cpB = cp_sh[p1c];
        const float* erA = ebase + (size_t)p0 * NC;
        const float* erB = ebase + (size_t)p1c * NC;
        float4 eA = act ? *(const float4*)(erA + 4 * lane) : make_float4(-1e30f, -1e30f, -1e30f, -1e30f);
        float4 eB = act ? *(const float4*)(erB + 4 * lane) : make_float4(-1e30f, -1e30f, -1e30f, -1e30f);

        // searchsorted 'left' = count(c_axis < cp) via ballot+popcount
        int cntA = __popcll(__ballot(ca.x < cpA)) + __popcll(__ballot(ca.y < cpA))
                 + __popcll(__ballot(ca.z < cpA)) + __popcll(__ballot(ca.w < cpA));
        int cntB = __popcll(__ballot(ca.x < cpB)) + __popcll(__ballot(ca.y < cpB))
                 + __popcll(__ballot(ca.z < cpB)) + __popcll(__ballot(ca.w < cpB));

        // row max: butterfly, two independent chains interleaved
        float mA = fmaxf(fmaxf(eA.x, eA.y), fmaxf(eA.z, eA.w));
        float mB = fmaxf(fmaxf(eB.x, eB.y), fmaxf(eB.z, eB.w));
        #pragma unroll
        for (int m = 32; m; m >>= 1) {
            mA = fmaxf(mA, __shfl_xor(mA, m, 64));
            mB = fmaxf(mB, __shfl_xor(mB, m, 64));
        }

        int iA = cntA < 1 ? 1 : (cntA > NC - 1 ? NC - 1 : cntA);
        int iB = cntB < 1 ? 1 : (cntB > NC - 1 ? NC - 1 : cntB);

        // e0/e1 fetched from registers by shuffle (idx is wave-uniform)
        int a0 = iA - 1, a1 = iA, b0 = iB - 1, b1 = iB;
        float sA0 = ((a0 & 3) == 0) ? eA.x : ((a0 & 3) == 1) ? eA.y : ((a0 & 3) == 2) ? eA.z : eA.w;
        float sA1 = ((a1 & 3) == 0) ? eA.x : ((a1 & 3) == 1) ? eA.y : ((a1 & 3) == 2) ? eA.z : eA.w;
        float sB0 = ((b0 & 3) == 0) ? eB.x : ((b0 & 3) == 1) ? eB.y : ((b0 & 3) == 2) ? eB.z : eB.w;
        float sB1 = ((b1 & 3) == 0) ? eB.x : ((b1 & 3) == 1) ? eB.y : ((b1 & 3) == 2) ? eB.z : eB.w;
        float e0A = __shfl(sA0, a0 >> 2, 64), e1A = __shfl(sA1, a1 >> 2, 64);
        float e0B = __shfl(sB0, b0 >> 2, 64), e1B = __shfl(sB1, b1 >> 2, 64);

        float c0A = csh[a0], c1A = csh[a1];
        float c0B = csh[b0], c1B = csh[b1];
        float wA = (cpA - c0A) / (c1A - c0A + 1e-12f);
        float wB = (cpB - c0B) / (c1B - c0B + 1e-12f);
        float eiA = fmaf(wA, e1A - e0A, e0A);
        float eiB = fmaf(wB, e1B - e0B, e0B);
        local += mA - eiA;
        local += has1 ? (mB - eiB) : 0.f;
    }
    // every lane holds the identical wave-uniform sum
    if (lane == 0) red[wv] = local;
    __syncthreads();
    if (tid == 0)
        atomicAdd(&bins[blockIdx.x & (NBINS - 1)], red[0] + red[1] + red[2] + red[3]);
}

// ---------------- K4: final reduce of bins -> out ----------------
__global__ __launch_bounds__(256) void k4_final(const float* __restrict__ bins,
                                                float* __restrict__ out) {
    __shared__ float red[4];
    int tid = threadIdx.x;
    float s = 0.f;
    for (int i = tid; i < NBINS; i += 256) s += bins[i];
    #pragma unroll
    for (int m = 32; m; m >>= 1) s += __shfl_xor(s, m, 64);
    int lane = tid & 63, wv = tid >> 6;
    if (lane == 0) red[wv] = s;
    __syncthreads();
    if (tid == 0) out[0] = -(red[0] + red[1] + red[2] + red[3]);  // / SIGMA^2 == 1
}

extern "C" void kernel_launch(void* const* d_in, const int* in_sizes, int n_in,
                              void* d_out, int out_size, void* d_ws, size_t ws_size,
                              hipStream_t stream) {
    const float* Vs      = (const float*)d_in[0];
    const float* A       = (const float*)d_in[1];
    const float* energy  = (const float*)d_in[2];
    const float* c_axis  = (const float*)d_in[3];
    const float* thick   = (const float*)d_in[4];
    const float* periods = (const float*)d_in[5];
    float* out = (float*)d_out;

    float* ws      = (float*)d_ws;
    float* r_pad   = ws;                                        // 2 MB
    float* partial = r_pad + (size_t)NGRID * PP;                // 16*4096*50*4 = 13.1 MB
    float* bins    = partial + (size_t)NSPLIT * NOBS * NPERIODS;// 4 KB

    hipLaunchKernelGGL(k1_rpad, dim3((NGRID * 64) / 256), dim3(256), 0, stream,
                       Vs, thick, periods, r_pad, bins);
    hipLaunchKernelGGL(k2_gemm, dim3(NOBS / DOT, NSPLIT), dim3(256), 0, stream,
                       A, r_pad, partial);
    hipLaunchKernelGGL(k3_main, dim3(NOBS), dim3(256), 0, stream,
                       energy, c_axis, partial, bins);
    hipLaunchKernelGGL(k4_final, dim3(1), dim3(256), 0, stream, bins, out);
}

// Round 8
// 366.345 us; speedup vs baseline: 1.1049x; 1.0746x over previous
//
#include <hip/hip_runtime.h>

#define NGRID 8192
#define NLAYER 24
#define NPERIODS 50
#define NOBS 4096
#define NC 200
#define PP 64            // periods padded to 64 (r_pad layout)
#define NSPLIT 16        // g-splits across blockIdx.y in K2
#define SPLITG (NGRID / NSPLIT)       // 512 g per split
#define WPB 4            // waves per block in K2
#define GC (SPLITG / WPB)             // 128 g per wave
#define KG 16            // g subtile staged in LDS per wave
#define ASTR 20          // A-tile LDS stride: b128 reads = 2-way/phase aliasing (free, m136)
#define RSTR 64          // r-tile LDS row stride; reads are uniform-address broadcasts
#define DOT 128          // obs per block: each wave holds TWO 64-obs acc tiles
#define NBINS 1024
#define VREF 3.0f
#define WLDSF (DOT * ASTR + KG * RSTR)   // per-wave floats: 2560 + 1024 = 3584
#define K2LDSF (WPB * WLDSF)             // 14336 floats = 57344 B -> 2 blocks/CU

// ---------------- K1: r_pad[g][p] = 1/(0.92 * sum_l w[p][l]*Vs[g][l]); block 0 zeroes bins ----
__global__ __launch_bounds__(256) void k1_rpad(const float* __restrict__ Vs,
                                               const float* __restrict__ thick,
                                               const float* __restrict__ periods,
                                               float* __restrict__ r_pad,
                                               float* __restrict__ bins) {
    __shared__ float w_sh[NLAYER][NPERIODS];   // transposed: reads are conflict-free
    __shared__ float z_sh[NLAYER];
    int tid = threadIdx.x;
    if (blockIdx.x == 0) {
        for (int i = tid; i < NBINS; i += 256) bins[i] = 0.f;
    }
    if (tid < NLAYER) {
        float c = 0.f;
        for (int i = 0; i <= tid; ++i) c += thick[i];
        z_sh[tid] = c - 0.5f * thick[tid];
    }
    __syncthreads();
    if (tid < NPERIODS) {
        float ds = (VREF / 3.0f) * periods[tid];
        float tmp[NLAYER];
        float s = 0.f;
        #pragma unroll
        for (int l = 0; l < NLAYER; ++l) {
            float v = expf(-z_sh[l] / ds) * thick[l];
            tmp[l] = v; s += v;
        }
        float inv = 1.f / s;
        #pragma unroll
        for (int l = 0; l < NLAYER; ++l) w_sh[l][tid] = tmp[l] * inv;
    }
    __syncthreads();
    int idx = blockIdx.x * 256 + tid;          // idx = g*64 + p  (lanes share g -> broadcast Vs)
    int g = idx >> 6, p = idx & 63;
    float r = 0.f;
    if (p < NPERIODS) {
        const float4* vp = (const float4*)(Vs + (size_t)g * NLAYER);
        float s = 0.f;
        #pragma unroll
        for (int q = 0; q < NLAYER / 4; ++q) {
            float4 t = vp[q];
            s = fmaf(w_sh[4*q+0][p], t.x, s);
            s = fmaf(w_sh[4*q+1][p], t.y, s);
            s = fmaf(w_sh[4*q+2][p], t.z, s);
            s = fmaf(w_sh[4*q+3][p], t.w, s);
        }
        r = 1.0f / (0.92f * s);
    }
    r_pad[idx] = r;                            // fully coalesced, zero-padded p>=50
}

// ---------------- K2: partial[s][o][p] = sum_{g in split s} A[o][g]*r[g][p] ----------------
// R8: R4's spill-free skeleton (direct global->LDS staging with TRANSIENT temps; VGPR 80,
// WRITE 13MB clean) + the r-path moved from wave-uniform s_load (50 SGPRs/row, out-of-order
// SMEM -> lgkmcnt(0) full drains; R1-R5 evidence: VALUBusy stuck at 20-28%) to wave-private
// LDS read via uniform-address ds_read_b128 BROADCASTS (in-order DS class, partial lgkm
// waits, conflict-free). NO long-lived register staging buffers: R6/R7 proved 48 VGPRs
// pinned across the inner loop makes the allocator spill to scratch (142 MB writes,
// HBM-bound at 113-121us, insensitive to __launch_bounds__).
__global__ __launch_bounds__(256) void k2_gemm(const float* __restrict__ A,
                                               const float* __restrict__ r_pad,
                                               float* __restrict__ partial) {
    __shared__ float lds[K2LDSF];              // 57344 B
    int tid  = threadIdx.x;
    int lane = tid & 63;
    int wv   = __builtin_amdgcn_readfirstlane(tid >> 6);
    int o_base = blockIdx.x * DOT;
    int split  = blockIdx.y;
    float* Aw = lds + wv * WLDSF;
    float* Rw = Aw + DOT * ASTR;

    float acc0[NPERIODS], acc1[NPERIODS];
    #pragma unroll
    for (int p = 0; p < NPERIODS; ++p) { acc0[p] = 0.f; acc1[p] = 0.f; }

    int g_wave = split * SPLITG + wv * GC;

    #pragma unroll 1
    for (int kt = 0; kt < GC / KG; ++kt) {                 // 8 subtiles of 16 g
        int g0 = g_wave + kt * KG;
        // stage A: 128 obs x 16 g (8 float4/lane, transient temps only)
        #pragma unroll
        for (int s = 0; s < 8; ++s) {
            int f   = s * 64 + lane;
            int row = f >> 2;
            int c4  = (f & 3) * 4;
            *(float4*)(Aw + row * ASTR + c4) =
                *(const float4*)(A + (size_t)(o_base + row) * NGRID + g0 + c4);
        }
        // stage r: 16 g x 64 p (4 float4/lane, L2-hot source)
        #pragma unroll
        for (int s = 0; s < 4; ++s) {
            int idx = s * 64 + lane;
            int g   = idx >> 4;
            int p4  = (idx & 15) * 4;
            *(float4*)(Rw + g * RSTR + p4) =
                *(const float4*)(r_pad + (size_t)(g0 + g) * PP + p4);
        }
        // NO barrier: both tiles are wave-private; same-wave DS ordering suffices

        #pragma unroll 1
        for (int gg = 0; gg < KG; gg += 4) {
            float4 a0 = *(const float4*)(Aw + lane * ASTR + gg);
            float4 a1 = *(const float4*)(Aw + (64 + lane) * ASTR + gg);
            #pragma unroll
            for (int j = 0; j < 4; ++j) {
                float aj0 = (j == 0) ? a0.x : (j == 1) ? a0.y : (j == 2) ? a0.z : a0.w;
                float aj1 = (j == 0) ? a1.x : (j == 1) ? a1.y : (j == 2) ? a1.z : a1.w;
                const float* rj = Rw + (gg + j) * RSTR;    // uniform LDS addr -> broadcast
                #pragma unroll
                for (int q = 0; q < 12; ++q) {
                    float4 rv = *(const float4*)(rj + 4 * q);   // ds_read_b128 broadcast
                    acc0[4*q+0] = fmaf(aj0, rv.x, acc0[4*q+0]);
                    acc0[4*q+1] = fmaf(aj0, rv.y, acc0[4*q+1]);
                    acc0[4*q+2] = fmaf(aj0, rv.z, acc0[4*q+2]);
                    acc0[4*q+3] = fmaf(aj0, rv.w, acc0[4*q+3]);
                    acc1[4*q+0] = fmaf(aj1, rv.x, acc1[4*q+0]);
                    acc1[4*q+1] = fmaf(aj1, rv.y, acc1[4*q+1]);
                    acc1[4*q+2] = fmaf(aj1, rv.z, acc1[4*q+2]);
                    acc1[4*q+3] = fmaf(aj1, rv.w, acc1[4*q+3]);
                }
                float2 rv2 = *(const float2*)(rj + 48);
                acc0[48] = fmaf(aj0, rv2.x, acc0[48]);
                acc0[49] = fmaf(aj0, rv2.y, acc0[49]);
                acc1[48] = fmaf(aj1, rv2.x, acc1[48]);
                acc1[49] = fmaf(aj1, rv2.y, acc1[49]);
            }
        }
    }

    // epilogue: cross-wave reduce (4 waves, same 128 obs) in 4 fully-unrolled phases of 16 p
    float* outp = partial + (size_t)split * (NOBS * NPERIODS) + (size_t)o_base * NPERIODS;
    #pragma unroll
    for (int h = 0; h < 4; ++h) {
        __syncthreads();
        float* rw = lds + wv * (DOT * 17);                 // stride 17 (odd) -> conflict-free
        #pragma unroll
        for (int q = 0; q < 16; ++q) {
            int p = h * 16 + q;
            rw[lane * 17 + q]        = (p < NPERIODS) ? acc0[p] : 0.f;
            rw[(64 + lane) * 17 + q] = (p < NPERIODS) ? acc1[p] : 0.f;
        }
        __syncthreads();
        for (int e = tid; e < DOT * 16; e += 256) {
            int oo = e >> 4, q = e & 15;
            int p  = h * 16 + q;
            if (p < NPERIODS) {
                float v = 0.f;
                #pragma unroll
                for (int w2 = 0; w2 < WPB; ++w2) v += lds[w2 * (DOT * 17) + oo * 17 + q];
                outp[oo * NPERIODS + p] = v;
            }
        }
    }
}

// ---------------- K3: block per obs; fused k2b (cpred for own obs via LDS), ballot
//                      searchsorted, shuffle interp. No fences. ----------------
__global__ __launch_bounds__(256) void k3_main(const float* __restrict__ energy,
                                               const float* __restrict__ c_axis,
                                               const float* __restrict__ partial,
                                               float* __restrict__ bins) {
    __shared__ float csh[NC];
    __shared__ float cp_sh[64];
    __shared__ float red[4];
    int tid  = threadIdx.x;
    int lane = tid & 63;
    int wv   = tid >> 6;
    int o    = blockIdx.x;

    if (tid < NC) csh[tid] = c_axis[(size_t)o * NC + tid];
    // fused k2b: cpred for THIS obs only (16x50 coalesced loads; kernel boundary = sync)
    if (tid >= 192) {
        int p = tid - 192;
        float v = 0.f;
        if (p < NPERIODS) {
            float s = 0.f;
            #pragma unroll
            for (int sp = 0; sp < NSPLIT; ++sp)
                s += partial[(size_t)sp * (NOBS * NPERIODS) + (size_t)o * NPERIODS + p];
            v = 1.0f / s;
        }
        cp_sh[p] = v;
    }
    __syncthreads();

    bool act = lane < NC / 4;                  // 50 active lanes
    float4 ca = act ? *(const float4*)(csh + 4 * lane) : make_float4(9e30f, 9e30f, 9e30f, 9e30f);
    const float* ebase = energy + (size_t)o * NPERIODS * NC;
    float local = 0.f;

    for (int p0 = wv; p0 < NPERIODS; p0 += 8) {
        int p1 = p0 + 4;
        bool has1 = p1 < NPERIODS;
        int p1c = has1 ? p1 : p0;
        float cpA = cp_sh[p0];
        float cpB = cp_sh[p1c];
        const float* erA = ebase + (size_t)p0 * NC;
        const float* erB = ebase + (size_t)p1c * NC;
        float4 eA = act ? *(const float4*)(erA + 4 * lane) : make_float4(-1e30f, -1e30f, -1e30f, -1e30f);
        float4 eB = act ? *(const float4*)(erB + 4 * lane) : make_float4(-1e30f, -1e30f, -1e30f, -1e30f);

        // searchsorted 'left' = count(c_axis < cp) via ballot+popcount
        int cntA = __popcll(__ballot(ca.x < cpA)) + __popcll(__ballot(ca.y < cpA))
                 + __popcll(__ballot(ca.z < cpA)) + __popcll(__ballot(ca.w < cpA));
        int cntB = __popcll(__ballot(ca.x < cpB)) + __popcll(__ballot(ca.y < cpB))
                 + __popcll(__ballot(ca.z < cpB)) + __popcll(__ballot(ca.w < cpB));

        // row max: butterfly, two independent chains interleaved
        float mA = fmaxf(fmaxf(eA.x, eA.y), fmaxf(eA.z, eA.w));
        float mB = fmaxf(fmaxf(eB.x, eB.y), fmaxf(eB.z, eB.w));
        #pragma unroll
        for (int m = 32; m; m >>= 1) {
            mA = fmaxf(mA, __shfl_xor(mA, m, 64));
            mB = fmaxf(mB, __shfl_xor(mB, m, 64));
        }

        int iA = cntA < 1 ? 1 : (cntA > NC - 1 ? NC - 1 : cntA);
        int iB = cntB < 1 ? 1 : (cntB > NC - 1 ? NC - 1 : cntB);

        // e0/e1 fetched from registers by shuffle (idx is wave-uniform)
        int a0 = iA - 1, a1 = iA, b0 = iB - 1, b1 = iB;
        float sA0 = ((a0 & 3) == 0) ? eA.x : ((a0 & 3) == 1) ? eA.y : ((a0 & 3) == 2) ? eA.z : eA.w;
        float sA1 = ((a1 & 3) == 0) ? eA.x : ((a1 & 3) == 1) ? eA.y : ((a1 & 3) == 2) ? eA.z : eA.w;
        float sB0 = ((b0 & 3) == 0) ? eB.x : ((b0 & 3) == 1) ? eB.y : ((b0 & 3) == 2) ? eB.z : eB.w;
        float sB1 = ((b1 & 3) == 0) ? eB.x : ((b1 & 3) == 1) ? eB.y : ((b1 & 3) == 2) ? eB.z : eB.w;
        float e0A = __shfl(sA0, a0 >> 2, 64), e1A = __shfl(sA1, a1 >> 2, 64);
        float e0B = __shfl(sB0, b0 >> 2, 64), e1B = __shfl(sB1, b1 >> 2, 64);

        float c0A = csh[a0], c1A = csh[a1];
        float c0B = csh[b0], c1B = csh[b1];
        float wA = (cpA - c0A) / (c1A - c0A + 1e-12f);
        float wB = (cpB - c0B) / (c1B - c0B + 1e-12f);
        float eiA = fmaf(wA, e1A - e0A, e0A);
        float eiB = fmaf(wB, e1B - e0B, e0B);
        local += mA - eiA;
        local += has1 ? (mB - eiB) : 0.f;
    }
    // every lane holds the identical wave-uniform sum
    if (lane == 0) red[wv] = local;
    __syncthreads();
    if (tid == 0)
        atomicAdd(&bins[blockIdx.x & (NBINS - 1)], red[0] + red[1] + red[2] + red[3]);
}

// ---------------- K4: final reduce of bins -> out ----------------
__global__ __launch_bounds__(256) void k4_final(const float* __restrict__ bins,
                                                float* __restrict__ out) {
    __shared__ float red[4];
    int tid = threadIdx.x;
    float s = 0.f;
    for (int i = tid; i < NBINS; i += 256) s += bins[i];
    #pragma unroll
    for (int m = 32; m; m >>= 1) s += __shfl_xor(s, m, 64);
    int lane = tid & 63, wv = tid >> 6;
    if (lane == 0) red[wv] = s;
    __syncthreads();
    if (tid == 0) out[0] = -(red[0] + red[1] + red[2] + red[3]);  // / SIGMA^2 == 1
}

extern "C" void kernel_launch(void* const* d_in, const int* in_sizes, int n_in,
                              void* d_out, int out_size, void* d_ws, size_t ws_size,
                              hipStream_t stream) {
    const float* Vs      = (const float*)d_in[0];
    const float* A       = (const float*)d_in[1];
    const float* energy  = (const float*)d_in[2];
    const float* c_axis  = (const float*)d_in[3];
    const float* thick   = (const float*)d_in[4];
    const float* periods = (const float*)d_in[5];
    float* out = (float*)d_out;

    float* ws      = (float*)d_ws;
    float* r_pad   = ws;                                        // 2 MB
    float* partial = r_pad + (size_t)NGRID * PP;                // 16*4096*50*4 = 13.1 MB
    float* bins    = partial + (size_t)NSPLIT * NOBS * NPERIODS;// 4 KB

    hipLaunchKernelGGL(k1_rpad, dim3((NGRID * 64) / 256), dim3(256), 0, stream,
                       Vs, thick, periods, r_pad, bins);
    hipLaunchKernelGGL(k2_gemm, dim3(NOBS / DOT, NSPLIT), dim3(256), 0, stream,
                       A, r_pad, partial);
    hipLaunchKernelGGL(k3_main, dim3(NOBS), dim3(256), 0, stream,
                       energy, c_axis, partial, bins);
    hipLaunchKernelGGL(k4_final, dim3(1), dim3(256), 0, stream, bins, out);
}